// Round 1
// baseline (615.146 us; speedup 1.0000x reference)
//
#include <hip/hip_runtime.h>

// LMMD loss on MI355X.
// loss = (1/n_idx) * sum_{p,q in [0,2B)} (v_p . v_q) * K(p,q)
//   v_i = s_vec[i] (i<B),  v_{B+j} = -t_vec[j]
//   K(p,q) = sum_{t<5} exp(-relu(sq_p+sq_q-2 x_p.x_q) * inv_d[t])
// Upper-triangle tiles only (K, w symmetric), factor 2 off-diagonal.

#define B 4096
#define D 256
#define C 31
#define N2 8192  // 2*B
#define TS 64
#define BK 32

struct WS {
  double acc_loss;
  double M[D];          // column sums of total
  float inv_d[5];
  float inv_n_idx;
  float s_div[32];      // mask[c]/s_cnt[c]
  float t_div[32];      // mask[c]/t_cnt_adj[c]
  float sq[N2];
  float v[(size_t)N2 * 32];  // v_p padded to 32 cols (col 31 = 0)
};

__global__ void k0_init(WS* __restrict__ ws) {
  int tid = threadIdx.x;
  if (tid == 0) ws->acc_loss = 0.0;
  if (tid < D) ws->M[tid] = 0.0;
}

__global__ void k1_stats(const int* __restrict__ s_label,
                         const float* __restrict__ t_label,
                         WS* __restrict__ ws) {
  __shared__ int ls_cnt[32];
  __shared__ float lt_cnt[32];
  __shared__ int lpres[32];
  __shared__ int lmask[32];
  int tid = threadIdx.x;  // 256 threads
  if (tid < 32) { ls_cnt[tid] = 0; lt_cnt[tid] = 0.f; lpres[tid] = 0; }
  __syncthreads();
  float tc[C];
#pragma unroll
  for (int c = 0; c < C; ++c) tc[c] = 0.f;
  for (int i = tid; i < B; i += 256) {
    atomicAdd(&ls_cnt[s_label[i]], 1);
    const float* row = t_label + (size_t)i * C;
    float best = row[0];
    int barg = 0;
    tc[0] += row[0];
#pragma unroll
    for (int c = 1; c < C; ++c) {
      float x = row[c];
      tc[c] += x;
      if (x > best) { best = x; barg = c; }  // strict > == jnp.argmax first-max
    }
    lpres[barg] = 1;  // benign race, all write 1
  }
#pragma unroll
  for (int c = 0; c < C; ++c) atomicAdd(&lt_cnt[c], tc[c]);
  __syncthreads();
  if (tid < 32) {
    int cnt = ls_cnt[tid];
    int m = (tid < C) && (cnt > 0) && (lpres[tid] != 0);
    lmask[tid] = m;
    ws->s_div[tid] = m ? 1.f / (float)cnt : 0.f;
    float t = lt_cnt[tid];
    float tadj = (t == 0.f) ? 100.f : t;
    ws->t_div[tid] = m ? 1.f / tadj : 0.f;
  }
  __syncthreads();
  if (tid == 0) {
    int s = 0;
    for (int c = 0; c < C; ++c) s += lmask[c];
    ws->inv_n_idx = 1.f / fmaxf((float)s, 1.f);
  }
}

// One block per row p: sq[p] and the 32-wide v row.
__global__ void k2_rows(const float* __restrict__ src,
                        const float* __restrict__ tgt,
                        const int* __restrict__ s_label,
                        const float* __restrict__ t_label,
                        WS* __restrict__ ws) {
  int p = blockIdx.x;
  int tid = threadIdx.x;  // 256 == D
  const float* row = (p < B) ? src + (size_t)p * D : tgt + (size_t)(p - B) * D;
  float x = row[tid];
  float s = x * x;
#pragma unroll
  for (int off = 32; off; off >>= 1) s += __shfl_down(s, off, 64);
  __shared__ float part[4];
  if ((tid & 63) == 0) part[tid >> 6] = s;
  __syncthreads();
  if (tid == 0) ws->sq[p] = part[0] + part[1] + part[2] + part[3];
  if (tid < 32) {
    float val = 0.f;
    if (tid < C) {
      if (p < B)
        val = (s_label[p] == tid) ? ws->s_div[tid] : 0.f;
      else
        val = -t_label[(size_t)(p - B) * C + tid] * ws->t_div[tid];
    }
    ws->v[(size_t)p * 32 + tid] = val;
  }
}

// Column sums of total (for analytic sum(l2)).
__global__ void k2_cols(const float* __restrict__ src,
                        const float* __restrict__ tgt,
                        WS* __restrict__ ws) {
  int d = threadIdx.x;  // 256
  int r0 = blockIdx.x * 256;
  double acc = 0.0;
  for (int r = r0; r < r0 + 256; ++r) {
    const float* row = (r < B) ? src + (size_t)r * D : tgt + (size_t)(r - B) * D;
    acc += (double)row[d];
  }
  atomicAdd(&ws->M[d], acc);
}

__global__ void k2b_bw(WS* __restrict__ ws) {
  int tid = threadIdx.x;  // 256
  double s = 0.0;
  for (int p = tid; p < N2; p += 256) s += (double)ws->sq[p];
#pragma unroll
  for (int off = 32; off; off >>= 1) s += __shfl_down(s, off, 64);
  __shared__ double part[4];
  if ((tid & 63) == 0) part[tid >> 6] = s;
  __syncthreads();
  if (tid == 0) {
    double S1 = part[0] + part[1] + part[2] + part[3];
    double msum = 0.0;
    for (int d = 0; d < D; ++d) { double m = ws->M[d]; msum += m * m; }
    double n = (double)N2;
    double sum_l2 = 2.0 * n * S1 - 2.0 * msum;
    double bw = sum_l2 / (n * n - n);
    bw = fmax(bw, 1e-6) / 4.0;  // KERNEL_MUL^(KERNEL_NUM//2) = 2^2
    for (int i = 0; i < 5; ++i) {
      double dc = fmax(bw * (double)(1 << i), 1e-6);
      ws->inv_d[i] = (float)(1.0 / dc);
    }
  }
}

// Main pairwise pass. Grid 128x128 tile pairs; lower-triangle blocks exit.
__global__ void k3_main(const float* __restrict__ src,
                        const float* __restrict__ tgt,
                        WS* __restrict__ ws) {
  int bq = blockIdx.x, bp = blockIdx.y;
  if (bq < bp) return;
  __shared__ float Ash[BK][TS + 2];  // stride 66: staging writes 2-way (free)
  __shared__ float Bsh[BK][TS + 2];
  int tid = threadIdx.x;             // 256
  int tx = tid & 15, ty = tid >> 4;  // 16x16 threads, 4x4 micro-tile
  int p0 = bp * TS, q0 = bq * TS;

  float acc[4][4] = {{0.f}};
  float wacc[4][4] = {{0.f}};

  float inv_d[5];
#pragma unroll
  for (int i = 0; i < 5; ++i) inv_d[i] = ws->inv_d[i];

  // ---- dot-product accumulation over D ----
  for (int k0 = 0; k0 < D; k0 += BK) {
    __syncthreads();
#pragma unroll
    for (int e = 0; e < 8; ++e) {
      int idx = e * 256 + tid;
      int r = idx >> 5, k = idx & 31;
      int gp = p0 + r;
      const float* rp = (gp < B) ? src + (size_t)gp * D : tgt + (size_t)(gp - B) * D;
      Ash[k][r] = rp[k0 + k];
      int gq = q0 + r;
      const float* rq = (gq < B) ? src + (size_t)gq * D : tgt + (size_t)(gq - B) * D;
      Bsh[k][r] = rq[k0 + k];
    }
    __syncthreads();
#pragma unroll
    for (int k = 0; k < BK; ++k) {
      float a[4], b[4];
#pragma unroll
      for (int ii = 0; ii < 4; ++ii) a[ii] = Ash[k][ty * 4 + ii];
#pragma unroll
      for (int jj = 0; jj < 4; ++jj) b[jj] = Bsh[k][tx * 4 + jj];
#pragma unroll
      for (int ii = 0; ii < 4; ++ii)
#pragma unroll
        for (int jj = 0; jj < 4; ++jj)
          acc[ii][jj] = fmaf(a[ii], b[jj], acc[ii][jj]);
    }
  }

  // ---- weight dot (31-dim, padded to 32) ----
  __syncthreads();
  const float* vmat = ws->v;
#pragma unroll
  for (int e = 0; e < 8; ++e) {
    int idx = e * 256 + tid;
    int r = idx >> 5, k = idx & 31;
    Ash[k][r] = vmat[(size_t)(p0 + r) * 32 + k];
    Bsh[k][r] = vmat[(size_t)(q0 + r) * 32 + k];
  }
  __syncthreads();
#pragma unroll
  for (int k = 0; k < BK; ++k) {
    float a[4], b[4];
#pragma unroll
    for (int ii = 0; ii < 4; ++ii) a[ii] = Ash[k][ty * 4 + ii];
#pragma unroll
    for (int jj = 0; jj < 4; ++jj) b[jj] = Bsh[k][tx * 4 + jj];
#pragma unroll
    for (int ii = 0; ii < 4; ++ii)
#pragma unroll
      for (int jj = 0; jj < 4; ++jj)
        wacc[ii][jj] = fmaf(a[ii], b[jj], wacc[ii][jj]);
  }

  // ---- epilogue: l2 -> 5-term exp kernel -> weighted sum ----
  float sqp[4], sqq[4];
#pragma unroll
  for (int ii = 0; ii < 4; ++ii) sqp[ii] = ws->sq[p0 + ty * 4 + ii];
#pragma unroll
  for (int jj = 0; jj < 4; ++jj) sqq[jj] = ws->sq[q0 + tx * 4 + jj];

  bool ondiag = (bp == bq);
  double local = 0.0;
#pragma unroll
  for (int ii = 0; ii < 4; ++ii) {
#pragma unroll
    for (int jj = 0; jj < 4; ++jj) {
      int p = p0 + ty * 4 + ii, q = q0 + tx * 4 + jj;
      float l2 = fmaxf(sqp[ii] + sqq[jj] - 2.f * acc[ii][jj], 0.f);
      float kern = 0.f;
#pragma unroll
      for (int t = 0; t < 5; ++t) kern += __expf(-l2 * inv_d[t]);
      float f = 2.0f;
      if (ondiag) f = (q > p) ? 2.f : ((q == p) ? 1.f : 0.f);
      local += (double)(wacc[ii][jj] * kern * f);
    }
  }
#pragma unroll
  for (int off = 32; off; off >>= 1) local += __shfl_down(local, off, 64);
  __shared__ double red[4];
  if ((tid & 63) == 0) red[tid >> 6] = local;
  __syncthreads();
  if (tid == 0) atomicAdd(&ws->acc_loss, red[0] + red[1] + red[2] + red[3]);
}

__global__ void k4_out(WS* __restrict__ ws, float* __restrict__ out) {
  out[0] = (float)(ws->acc_loss * (double)ws->inv_n_idx);
}

extern "C" void kernel_launch(void* const* d_in, const int* in_sizes, int n_in,
                              void* d_out, int out_size, void* d_ws, size_t ws_size,
                              hipStream_t stream) {
  const float* src = (const float*)d_in[0];
  const float* tgt = (const float*)d_in[1];
  const int* s_label = (const int*)d_in[2];
  const float* t_label = (const float*)d_in[3];
  float* out = (float*)d_out;
  WS* ws = (WS*)d_ws;

  k0_init<<<1, 256, 0, stream>>>(ws);
  k1_stats<<<1, 256, 0, stream>>>(s_label, t_label, ws);
  k2_rows<<<N2, 256, 0, stream>>>(src, tgt, s_label, t_label, ws);
  k2_cols<<<32, 256, 0, stream>>>(src, tgt, ws);
  k2b_bw<<<1, 256, 0, stream>>>(ws);
  dim3 g3(N2 / TS, N2 / TS);
  k3_main<<<g3, 256, 0, stream>>>(src, tgt, ws);
  k4_out<<<1, 1, 0, stream>>>(ws, out);
}

// Round 2
// 293.912 us; speedup vs baseline: 2.0930x; 2.0930x over previous
//
#include <hip/hip_runtime.h>

// LMMD loss, MFMA bf16 hi/lo split.
// loss = (1/n_idx) * sum_{p<=q} f_pq * (v_p . v_q) * K(p,q),  f=2 off-diag, 1 diag
//   v_i = s_vec[i] (i<B),  v_{B+j} = -t_vec[j]
//   K(p,q) = sum_{t<5} y4^(2^(4-t)),  y4 = exp(-l2 * inv_d4)   (dc ratios are exact 2x)
// Dot products via mfma_f32_16x16x32_bf16 with x = hi + lo split:
//   x_p.x_q ~= hi.hi + hi.lo + lo.hi   (24 feature K-chunks of 32)
// Weight dot v_p.v_q likewise (3 K-chunks of 32) into a second accumulator.

#define B 4096
#define D 256
#define C 31
#define N2 8192
#define G 64                 // 128-row tiles per dim
#define NBLK (G * (G + 1) / 2)  // 2080 upper-tri tile pairs

typedef __attribute__((ext_vector_type(8))) short bf16x8;
typedef __attribute__((ext_vector_type(4))) float f32x4;

struct WS {
  double acc_loss;
  int s_cnt[32];
  float t_cnt[32];
  int t_pres[32];
  float s_div[32], t_div[32];
  float inv_n_idx;
  float inv_d4;
  float sq[N2];
  float Mpart[256 * 256];  // per-block column partial sums
  alignas(16) unsigned short Thi[(size_t)N2 * D];
  alignas(16) unsigned short Tlo[(size_t)N2 * D];
  alignas(16) unsigned short vhi[(size_t)N2 * 32];
  alignas(16) unsigned short vlo[(size_t)N2 * 32];
};

static __device__ __forceinline__ unsigned short f2bf(float f) {
  unsigned int u = __float_as_uint(f);
  unsigned int r = (u + 0x7fffu + ((u >> 16) & 1u)) >> 16;  // RNE
  return (unsigned short)r;
}
static __device__ __forceinline__ float bf2f(unsigned short s) {
  return __uint_as_float(((unsigned int)s) << 16);
}

#define GLD16(gsrc, ldst)                                                     \
  __builtin_amdgcn_global_load_lds(                                           \
      (const __attribute__((address_space(1))) void*)(gsrc),                  \
      (__attribute__((address_space(3))) void*)(ldst), 16, 0, 0)

__global__ void k0_init(WS* __restrict__ ws) {
  int tid = threadIdx.x;  // 64
  if (tid == 0) ws->acc_loss = 0.0;
  if (tid < 32) {
    ws->s_cnt[tid] = 0;
    ws->t_cnt[tid] = 0.f;
    ws->t_pres[tid] = 0;
  }
}

__global__ void kA1_stats(const int* __restrict__ s_label,
                          const float* __restrict__ t_label,
                          WS* __restrict__ ws) {
  __shared__ int ls[32];
  __shared__ float lt[32];
  __shared__ int lp[32];
  int tid = threadIdx.x;  // 256, 16 blocks
  if (tid < 32) { ls[tid] = 0; lt[tid] = 0.f; lp[tid] = 0; }
  __syncthreads();
  int row = blockIdx.x * 256 + tid;
  atomicAdd(&ls[s_label[row]], 1);
  const float* r = t_label + (size_t)row * C;
  float best = -1e30f;
  int barg = 0;
#pragma unroll
  for (int c = 0; c < C; ++c) {
    float x = r[c];
    atomicAdd(&lt[c], x);
    if (x > best) { best = x; barg = c; }  // first-max == jnp.argmax
  }
  lp[barg] = 1;
  __syncthreads();
  if (tid < 32) {
    if (ls[tid]) atomicAdd(&ws->s_cnt[tid], ls[tid]);
    atomicAdd(&ws->t_cnt[tid], lt[tid]);
    if (lp[tid]) ws->t_pres[tid] = 1;
  }
}

__global__ void kA2_final(WS* __restrict__ ws) {
  int tid = threadIdx.x;  // 64 (one wave)
  int m = 0;
  if (tid < 32) {
    int cnt = ws->s_cnt[tid];
    m = (tid < C) && (cnt > 0) && (ws->t_pres[tid] != 0);
    ws->s_div[tid] = m ? 1.f / (float)cnt : 0.f;
    float t = ws->t_cnt[tid];
    float ta = (t == 0.f) ? 100.f : t;
    ws->t_div[tid] = m ? 1.f / ta : 0.f;
  }
  unsigned long long bal = __ballot(m);
  if (tid == 0) {
    int cnt = __popcll(bal);
    ws->inv_n_idx = 1.f / fmaxf((float)cnt, 1.f);
  }
}

// Prep: hi/lo conversion, sq, column partial sums, v hi/lo.
// 256 blocks x 256 threads; block handles 32 consecutive rows of "total".
__global__ __launch_bounds__(256) void kB_prep(const float* __restrict__ src,
                                               const float* __restrict__ tgt,
                                               const int* __restrict__ s_label,
                                               const float* __restrict__ t_label,
                                               WS* __restrict__ ws) {
  int tid = threadIdx.x, w = tid >> 6, lane = tid & 63;
  int r0 = blockIdx.x * 32;
  __shared__ float rsq[32];
  __shared__ float colp[4][256];
  float ca0 = 0.f, ca1 = 0.f, ca2 = 0.f, ca3 = 0.f;
#pragma unroll
  for (int i = 0; i < 8; ++i) {
    int rr = w * 8 + i;
    int p = r0 + rr;
    const float* rp = (p < B) ? src + (size_t)p * D : tgt + (size_t)(p - B) * D;
    float4 x = *(const float4*)(rp + lane * 4);
    unsigned short h0 = f2bf(x.x), h1 = f2bf(x.y), h2 = f2bf(x.z), h3 = f2bf(x.w);
    unsigned short l0 = f2bf(x.x - bf2f(h0)), l1 = f2bf(x.y - bf2f(h1));
    unsigned short l2_ = f2bf(x.z - bf2f(h2)), l3 = f2bf(x.w - bf2f(h3));
    ushort4 hv; hv.x = h0; hv.y = h1; hv.z = h2; hv.w = h3;
    ushort4 lv; lv.x = l0; lv.y = l1; lv.z = l2_; lv.w = l3;
    *(ushort4*)(&ws->Thi[(size_t)p * D + lane * 4]) = hv;
    *(ushort4*)(&ws->Tlo[(size_t)p * D + lane * 4]) = lv;
    ca0 += x.x; ca1 += x.y; ca2 += x.z; ca3 += x.w;
    float s = x.x * x.x + x.y * x.y + x.z * x.z + x.w * x.w;
#pragma unroll
    for (int off = 32; off; off >>= 1) s += __shfl_down(s, off, 64);
    if (lane == 0) rsq[rr] = s;
  }
  colp[w][lane * 4 + 0] = ca0;
  colp[w][lane * 4 + 1] = ca1;
  colp[w][lane * 4 + 2] = ca2;
  colp[w][lane * 4 + 3] = ca3;
  __syncthreads();
  if (tid < 32) ws->sq[r0 + tid] = rsq[tid];
  ws->Mpart[(size_t)blockIdx.x * 256 + tid] =
      colp[0][tid] + colp[1][tid] + colp[2][tid] + colp[3][tid];
  // v rows: thread handles 4 class-columns of one row
  int vr = tid >> 3, cb = (tid & 7) * 4;
  int p = r0 + vr;
  ushort4 vh, vl;
  unsigned short vhs[4], vls[4];
#pragma unroll
  for (int j = 0; j < 4; ++j) {
    int c = cb + j;
    float val = 0.f;
    if (c < C) {
      if (p < B)
        val = (s_label[p] == c) ? ws->s_div[c] : 0.f;
      else
        val = -t_label[(size_t)(p - B) * C + c] * ws->t_div[c];
    }
    unsigned short h = f2bf(val);
    vhs[j] = h;
    vls[j] = f2bf(val - bf2f(h));
  }
  vh.x = vhs[0]; vh.y = vhs[1]; vh.z = vhs[2]; vh.w = vhs[3];
  vl.x = vls[0]; vl.y = vls[1]; vl.z = vls[2]; vl.w = vls[3];
  *(ushort4*)(&ws->vhi[(size_t)p * 32 + cb]) = vh;
  *(ushort4*)(&ws->vlo[(size_t)p * 32 + cb]) = vl;
}

__global__ void kC_bw(WS* __restrict__ ws) {
  int tid = threadIdx.x;  // 256
  double s = 0.0;
  for (int p = tid; p < N2; p += 256) s += (double)ws->sq[p];
  double col = 0.0;
  for (int b = 0; b < 256; ++b) col += (double)ws->Mpart[(size_t)b * 256 + tid];
  double m2 = col * col;
#pragma unroll
  for (int off = 32; off; off >>= 1) {
    s += __shfl_down(s, off, 64);
    m2 += __shfl_down(m2, off, 64);
  }
  __shared__ double ps[4], pm[4];
  if ((tid & 63) == 0) { ps[tid >> 6] = s; pm[tid >> 6] = m2; }
  __syncthreads();
  if (tid == 0) {
    double S = ps[0] + ps[1] + ps[2] + ps[3];
    double M2 = pm[0] + pm[1] + pm[2] + pm[3];
    double n = (double)N2;
    double sum_l2 = 2.0 * n * S - 2.0 * M2;
    double bw = sum_l2 / (n * n - n);
    bw = fmax(bw, 1e-6) * 0.25;           // /KERNEL_MUL^2
    double dc4 = fmax(bw * 16.0, 1e-6);   // largest denom
    ws->inv_d4 = (float)(1.0 / dc4);
  }
}

// Main MFMA pass: 128x128 output tile per block, 27 K-chunks of 32
// (24 feature hi/lo chunks -> acc, 3 weight hi/lo chunks -> wacc).
__global__ __launch_bounds__(256, 2) void k3_main(WS* __restrict__ ws) {
  int tid = threadIdx.x, w = tid >> 6, lane = tid & 63;
  // decode upper-triangular (bp <= bq) from linear block id
  int lin = blockIdx.x;
  int bp = (int)((2.0 * G + 1.0 -
                  sqrt((2.0 * G + 1.0) * (2.0 * G + 1.0) - 8.0 * (double)lin)) *
                 0.5);
  while ((bp + 1) * G - ((bp + 1) * bp) / 2 <= lin) ++bp;
  while (bp * G - (bp * (bp - 1)) / 2 > lin) --bp;
  int bq = bp + (lin - (bp * G - (bp * (bp - 1)) / 2));
  int p0 = bp * 128, q0 = bq * 128;

  __shared__ __align__(16) unsigned short Ash[128 * 32];
  __shared__ __align__(16) unsigned short Bsh[128 * 32];

  const int wr = (w >> 1) * 64, wc = (w & 1) * 64;
  f32x4 acc[4][4], wacc[4][4];
#pragma unroll
  for (int i = 0; i < 4; ++i)
#pragma unroll
    for (int j = 0; j < 4; ++j) {
      acc[i][j] = (f32x4){0.f, 0.f, 0.f, 0.f};
      wacc[i][j] = (f32x4){0.f, 0.f, 0.f, 0.f};
    }

  const unsigned short* Thi = ws->Thi;
  const unsigned short* Tlo = ws->Tlo;
  const unsigned short* vhi = ws->vhi;
  const unsigned short* vlo = ws->vlo;

  int rA = tid >> 2;            // staging row 0..63
  int cp8 = (tid & 3) * 8;      // staging col offset (shorts)
  unsigned short* ldsA = Ash + w * 512;  // wave-uniform base
  unsigned short* ldsB = Bsh + w * 512;
  const int mrow = lane & 15, quad = lane >> 4;

  for (int c = 0; c < 27; ++c) {
    const unsigned short *sA, *sB;
    int str, k0;
    if (c < 24) {
      k0 = (c & 7) * 32;
      str = D;
      sA = (c < 16) ? Thi : Tlo;
      sB = (c < 8) ? Thi : ((c < 16) ? Tlo : Thi);
    } else {
      k0 = 0;
      str = 32;
      sA = (c == 26) ? vlo : vhi;
      sB = (c == 25) ? vlo : vhi;
    }
    __syncthreads();  // previous chunk's LDS reads done
    const unsigned short* gA0 = sA + (size_t)(p0 + rA) * str + k0 + cp8;
    const unsigned short* gB0 = sB + (size_t)(q0 + rA) * str + k0 + cp8;
    GLD16(gA0, ldsA);
    GLD16(gA0 + (size_t)64 * str, ldsA + 2048);
    GLD16(gB0, ldsB);
    GLD16(gB0 + (size_t)64 * str, ldsB + 2048);
    __syncthreads();  // staging complete (compiler drains vmcnt)

    bf16x8 af[4], bfr[4];
#pragma unroll
    for (int ti = 0; ti < 4; ++ti)
      af[ti] = *(const bf16x8*)(Ash + (wr + ti * 16 + mrow) * 32 + quad * 8);
#pragma unroll
    for (int tj = 0; tj < 4; ++tj)
      bfr[tj] = *(const bf16x8*)(Bsh + (wc + tj * 16 + mrow) * 32 + quad * 8);

    if (c < 24) {
#pragma unroll
      for (int ti = 0; ti < 4; ++ti)
#pragma unroll
        for (int tj = 0; tj < 4; ++tj)
          acc[ti][tj] = __builtin_amdgcn_mfma_f32_16x16x32_bf16(
              af[ti], bfr[tj], acc[ti][tj], 0, 0, 0);
    } else {
#pragma unroll
      for (int ti = 0; ti < 4; ++ti)
#pragma unroll
        for (int tj = 0; tj < 4; ++tj)
          wacc[ti][tj] = __builtin_amdgcn_mfma_f32_16x16x32_bf16(
              af[ti], bfr[tj], wacc[ti][tj], 0, 0, 0);
    }
  }

  // epilogue
  float c4 = ws->inv_d4;
  float sqq[4], sqp[4][4];
#pragma unroll
  for (int tj = 0; tj < 4; ++tj) sqq[tj] = ws->sq[q0 + wc + tj * 16 + mrow];
#pragma unroll
  for (int ti = 0; ti < 4; ++ti)
#pragma unroll
    for (int rg = 0; rg < 4; ++rg)
      sqp[ti][rg] = ws->sq[p0 + wr + ti * 16 + quad * 4 + rg];

  bool ondiag = (bp == bq);
  double local = 0.0;
#pragma unroll
  for (int ti = 0; ti < 4; ++ti) {
#pragma unroll
    for (int tj = 0; tj < 4; ++tj) {
#pragma unroll
      for (int rg = 0; rg < 4; ++rg) {
        int p = p0 + wr + ti * 16 + quad * 4 + rg;
        int q = q0 + wc + tj * 16 + mrow;
        float l2 = fmaxf(sqp[ti][rg] + sqq[tj] - 2.f * acc[ti][tj][rg], 0.f);
        float y = __expf(-l2 * c4);  // y4 (largest denom)
        float kv = y;
        y *= y; kv += y;
        y *= y; kv += y;
        y *= y; kv += y;
        y *= y; kv += y;  // y4 + y3 + y2 + y1 + y0
        float f = 2.f;
        if (ondiag) f = (q > p) ? 2.f : ((q == p) ? 1.f : 0.f);
        local += (double)(wacc[ti][tj][rg] * kv * f);
      }
    }
  }
#pragma unroll
  for (int off = 32; off; off >>= 1) local += __shfl_down(local, off, 64);
  __shared__ double red[4];
  if (lane == 0) red[w] = local;
  __syncthreads();
  if (tid == 0) atomicAdd(&ws->acc_loss, red[0] + red[1] + red[2] + red[3]);
}

__global__ void k4_out(WS* __restrict__ ws, float* __restrict__ out) {
  out[0] = (float)(ws->acc_loss * (double)ws->inv_n_idx);
}

extern "C" void kernel_launch(void* const* d_in, const int* in_sizes, int n_in,
                              void* d_out, int out_size, void* d_ws, size_t ws_size,
                              hipStream_t stream) {
  const float* src = (const float*)d_in[0];
  const float* tgt = (const float*)d_in[1];
  const int* s_label = (const int*)d_in[2];
  const float* t_label = (const float*)d_in[3];
  float* out = (float*)d_out;
  WS* ws = (WS*)d_ws;  // requires ws_size >= sizeof(WS) (~9.3 MB)

  k0_init<<<1, 64, 0, stream>>>(ws);
  kA1_stats<<<16, 256, 0, stream>>>(s_label, t_label, ws);
  kA2_final<<<1, 64, 0, stream>>>(ws);
  kB_prep<<<256, 256, 0, stream>>>(src, tgt, s_label, t_label, ws);
  kC_bw<<<1, 256, 0, stream>>>(ws);
  k3_main<<<NBLK, 256, 0, stream>>>(ws);
  k4_out<<<1, 1, 0, stream>>>(ws, out);
}

// Round 3
// 236.926 us; speedup vs baseline: 2.5964x; 1.2405x over previous
//
#include <hip/hip_runtime.h>

// LMMD loss, round 3.
// loss = (1/n_idx) * sum_{p<=q} f_pq * w_pq * K(p,q),  f=2 off-diag, 1 diag
//   w_pq = v_p . v_q,  v_i = s_vec[i] (i<B), v_{B+j} = -t_vec[j]  (rank-31)
//   K(p,q) = sum_t y^(2^t), y = exp(-l2 * inv_d4), l2 = relu(sq_p+sq_q-2 x_p.x_q)
// Features: bf16 hi-only MFMA (error ~1e-4 rel on K, zero-mean -> negligible).
// Weights: SS lookup (exact), ST single gather (exact), TT bf16 MFMA chunk.

#define B 4096
#define D 256
#define C 31
#define N2 8192

typedef __attribute__((ext_vector_type(8))) short bf16x8;
typedef __attribute__((ext_vector_type(4))) float f32x4;

struct WS {
  double acc_loss;
  int s_cnt[32];
  float t_cnt[32];
  int t_pres[32];
  float s_div[32], t_div[32];
  float inv_n_idx;
  float inv_d4;
  float sq[N2];
  int slab[N2];    // source label (rows < B), else 0
  float sdv[N2];   // s_div[label] (rows < B), else 0
  float Mpart[256 * 256];
  alignas(16) unsigned short Thi[(size_t)N2 * D];  // bf16 of x
  alignas(16) unsigned short vhi[(size_t)N2 * 32]; // bf16 of v
  alignas(16) float v[(size_t)N2 * 32];            // exact f32 v
};

static __device__ __forceinline__ unsigned short f2bf(float f) {
  unsigned int u = __float_as_uint(f);
  return (unsigned short)((u + 0x7fffu + ((u >> 16) & 1u)) >> 16);  // RNE
}

#define GLD16(gsrc, ldst)                                                     \
  __builtin_amdgcn_global_load_lds(                                           \
      (const __attribute__((address_space(1))) void*)(gsrc),                  \
      (__attribute__((address_space(3))) void*)(ldst), 16, 0, 0)

__global__ void k0_init(WS* __restrict__ ws) {
  int tid = threadIdx.x;  // 64
  if (tid == 0) ws->acc_loss = 0.0;
  if (tid < 32) {
    ws->s_cnt[tid] = 0;
    ws->t_cnt[tid] = 0.f;
    ws->t_pres[tid] = 0;
  }
}

__global__ void kA1_stats(const int* __restrict__ s_label,
                          const float* __restrict__ t_label,
                          WS* __restrict__ ws) {
  __shared__ int ls[32];
  __shared__ float lt[32];
  __shared__ int lp[32];
  int tid = threadIdx.x;  // 256, 16 blocks
  if (tid < 32) { ls[tid] = 0; lt[tid] = 0.f; lp[tid] = 0; }
  __syncthreads();
  int row = blockIdx.x * 256 + tid;
  atomicAdd(&ls[s_label[row]], 1);
  const float* r = t_label + (size_t)row * C;
  float best = -1e30f;
  int barg = 0;
#pragma unroll
  for (int c = 0; c < C; ++c) {
    float x = r[c];
    atomicAdd(&lt[c], x);
    if (x > best) { best = x; barg = c; }  // first-max == jnp.argmax
  }
  lp[barg] = 1;
  __syncthreads();
  if (tid < 32) {
    if (ls[tid]) atomicAdd(&ws->s_cnt[tid], ls[tid]);
    atomicAdd(&ws->t_cnt[tid], lt[tid]);
    if (lp[tid]) ws->t_pres[tid] = 1;
  }
}

__global__ void kA2_final(WS* __restrict__ ws) {
  int tid = threadIdx.x;  // 64
  int m = 0;
  if (tid < 32) {
    int cnt = ws->s_cnt[tid];
    m = (tid < C) && (cnt > 0) && (ws->t_pres[tid] != 0);
    ws->s_div[tid] = m ? 1.f / (float)cnt : 0.f;
    float t = ws->t_cnt[tid];
    float ta = (t == 0.f) ? 100.f : t;
    ws->t_div[tid] = m ? 1.f / ta : 0.f;
  }
  unsigned long long bal = __ballot(m);
  if (tid == 0) ws->inv_n_idx = 1.f / fmaxf((float)__popcll(bal), 1.f);
}

// Prep: Thi bf16, sq, column partials, v (f32 + bf16), slab/sdv.
__global__ __launch_bounds__(256) void kB_prep(const float* __restrict__ src,
                                               const float* __restrict__ tgt,
                                               const int* __restrict__ s_label,
                                               const float* __restrict__ t_label,
                                               WS* __restrict__ ws) {
  int tid = threadIdx.x, w = tid >> 6, lane = tid & 63;
  int r0 = blockIdx.x * 32;
  __shared__ float rsq[32];
  __shared__ float colp[4][256];
  float ca0 = 0.f, ca1 = 0.f, ca2 = 0.f, ca3 = 0.f;
#pragma unroll
  for (int i = 0; i < 8; ++i) {
    int rr = w * 8 + i;
    int p = r0 + rr;
    const float* rp = (p < B) ? src + (size_t)p * D : tgt + (size_t)(p - B) * D;
    float4 x = *(const float4*)(rp + lane * 4);
    ushort4 hv;
    hv.x = f2bf(x.x); hv.y = f2bf(x.y); hv.z = f2bf(x.z); hv.w = f2bf(x.w);
    *(ushort4*)(&ws->Thi[(size_t)p * D + lane * 4]) = hv;
    ca0 += x.x; ca1 += x.y; ca2 += x.z; ca3 += x.w;
    float s = x.x * x.x + x.y * x.y + x.z * x.z + x.w * x.w;
#pragma unroll
    for (int off = 32; off; off >>= 1) s += __shfl_down(s, off, 64);
    if (lane == 0) rsq[rr] = s;
  }
  colp[w][lane * 4 + 0] = ca0;
  colp[w][lane * 4 + 1] = ca1;
  colp[w][lane * 4 + 2] = ca2;
  colp[w][lane * 4 + 3] = ca3;
  __syncthreads();
  if (tid < 32) {
    int p = r0 + tid;
    ws->sq[p] = rsq[tid];
    if (p < B) {
      int lb = s_label[p];
      ws->slab[p] = lb;
      ws->sdv[p] = ws->s_div[lb];
    } else {
      ws->slab[p] = 0;
      ws->sdv[p] = 0.f;
    }
  }
  ws->Mpart[(size_t)blockIdx.x * 256 + tid] =
      colp[0][tid] + colp[1][tid] + colp[2][tid] + colp[3][tid];
  // v rows (f32 exact + bf16)
  int vr = tid >> 3, cb = (tid & 7) * 4;
  int p = r0 + vr;
  float vals[4];
#pragma unroll
  for (int j = 0; j < 4; ++j) {
    int c = cb + j;
    float val = 0.f;
    if (c < C) {
      if (p < B)
        val = (s_label[p] == c) ? ws->s_div[c] : 0.f;
      else
        val = -t_label[(size_t)(p - B) * C + c] * ws->t_div[c];
    }
    vals[j] = val;
  }
  float4 vf; vf.x = vals[0]; vf.y = vals[1]; vf.z = vals[2]; vf.w = vals[3];
  *(float4*)(&ws->v[(size_t)p * 32 + cb]) = vf;
  ushort4 vh;
  vh.x = f2bf(vals[0]); vh.y = f2bf(vals[1]);
  vh.z = f2bf(vals[2]); vh.w = f2bf(vals[3]);
  *(ushort4*)(&ws->vhi[(size_t)p * 32 + cb]) = vh;
}

__global__ void kC_bw(WS* __restrict__ ws) {
  int tid = threadIdx.x;  // 256
  double s = 0.0;
  for (int p = tid; p < N2; p += 256) s += (double)ws->sq[p];
  double col = 0.0;
  for (int b = 0; b < 256; ++b) col += (double)ws->Mpart[(size_t)b * 256 + tid];
  double m2 = col * col;
#pragma unroll
  for (int off = 32; off; off >>= 1) {
    s += __shfl_down(s, off, 64);
    m2 += __shfl_down(m2, off, 64);
  }
  __shared__ double ps[4], pm[4];
  if ((tid & 63) == 0) { ps[tid >> 6] = s; pm[tid >> 6] = m2; }
  __syncthreads();
  if (tid == 0) {
    double S = ps[0] + ps[1] + ps[2] + ps[3];
    double M2 = pm[0] + pm[1] + pm[2] + pm[3];
    double n = (double)N2;
    double sum_l2 = 2.0 * n * S - 2.0 * M2;
    double bw = sum_l2 / (n * n - n);
    bw = fmax(bw, 1e-6) * 0.25;
    double dc4 = fmax(bw * 16.0, 1e-6);
    ws->inv_d4 = (float)(1.0 / dc4);
  }
}

// ---- shared device helpers for the main kernels ----
#define FEATURE_LOOP(p0_, q0_)                                                 \
  for (int s = 0; s < 4; ++s) {                                                \
    int ks = s * 64;                                                           \
    __syncthreads();                                                           \
    _Pragma("unroll") for (int c = 0; c < 2; ++c) {                            \
      const unsigned short* gA =                                               \
          Thi + (size_t)((p0_) + rA) * D + ks + c * 32 + cp8;                  \
      GLD16(gA, ldsA + c * 4096);                                              \
      GLD16(gA + (size_t)64 * D, ldsA + c * 4096 + 2048);                      \
      const unsigned short* gB =                                               \
          Thi + (size_t)((q0_) + rA) * D + ks + c * 32 + cp8;                  \
      GLD16(gB, ldsB + c * 4096);                                              \
      GLD16(gB + (size_t)64 * D, ldsB + c * 4096 + 2048);                      \
    }                                                                          \
    __syncthreads();                                                           \
    _Pragma("unroll") for (int c = 0; c < 2; ++c) {                            \
      bf16x8 af[4], bfr[4];                                                    \
      _Pragma("unroll") for (int ti = 0; ti < 4; ++ti) af[ti] =                \
          *(const bf16x8*)(Ash + c * 4096 + (wr + ti * 16 + mrow) * 32 +       \
                           quad * 8);                                          \
      _Pragma("unroll") for (int tj = 0; tj < 4; ++tj) bfr[tj] =               \
          *(const bf16x8*)(Bsh + c * 4096 + (wc + tj * 16 + mrow) * 32 +       \
                           quad * 8);                                          \
      _Pragma("unroll") for (int ti = 0; ti < 4; ++ti)                         \
          _Pragma("unroll") for (int tj = 0; tj < 4; ++tj) acc[ti][tj] =       \
          __builtin_amdgcn_mfma_f32_16x16x32_bf16(af[ti], bfr[tj],             \
                                                  acc[ti][tj], 0, 0, 0);       \
    }                                                                          \
  }

// SS + ST blocks: bp < 32, bp <= bq <= 63.  1552 blocks.
__global__ __launch_bounds__(256, 3) void k3_ss_st(WS* __restrict__ ws) {
  int tid = threadIdx.x, w = tid >> 6;
  int lane = tid & 63;
  int lin = blockIdx.x;
  int bp = 0;
  while (64 * (bp + 1) - ((bp + 1) * bp) / 2 <= lin) ++bp;
  int bq = bp + (lin - (64 * bp - (bp * (bp - 1)) / 2));
  int p0 = bp * 128, q0 = bq * 128;
  bool is_st = (bq >= 32);

  __shared__ __align__(16) unsigned short Ash[2 * 128 * 32];
  __shared__ __align__(16) unsigned short Bsh[2 * 128 * 32];
  __shared__ __align__(16) float Vsh[128 * 40];
  __shared__ double red[4];

  const int wr = (w >> 1) * 64, wc = (w & 1) * 64;
  const int mrow = lane & 15, quad = lane >> 4;
  f32x4 acc[4][4];
#pragma unroll
  for (int i = 0; i < 4; ++i)
#pragma unroll
    for (int j = 0; j < 4; ++j) acc[i][j] = (f32x4){0.f, 0.f, 0.f, 0.f};

  const unsigned short* Thi = ws->Thi;
  int rA = tid >> 2, cp8 = (tid & 3) * 8;
  unsigned short* ldsA = Ash + w * 512;
  unsigned short* ldsB = Bsh + w * 512;

  FEATURE_LOOP(p0, q0)

  if (is_st) {
    // stage exact f32 V rows for the q (target) tile, padded stride 40
#pragma unroll
    for (int r4 = 0; r4 < 4; ++r4) {
      int r = r4 * 32 + (tid >> 3);
      int c4 = (tid & 7) * 4;
      *(float4*)(&Vsh[r * 40 + c4]) =
          *(const float4*)(&ws->v[(size_t)(q0 + r) * 32 + c4]);
    }
  }
  __syncthreads();  // V staged; also guards LDS reuse

  float cinv = ws->inv_d4;
  float sqq[4];
  int labq[4];
  float sdq[4];
#pragma unroll
  for (int tj = 0; tj < 4; ++tj) {
    int q = q0 + wc + tj * 16 + mrow;
    sqq[tj] = ws->sq[q];
    labq[tj] = ws->slab[q];
    sdq[tj] = ws->sdv[q];
  }
  bool ondiag = (bp == bq);
  float local = 0.f;
#pragma unroll
  for (int ti = 0; ti < 4; ++ti) {
#pragma unroll
    for (int rg = 0; rg < 4; ++rg) {
      int p = p0 + wr + ti * 16 + quad * 4 + rg;
      float sqp = ws->sq[p];
      int lp = ws->slab[p];
      float sp = ws->sdv[p];
#pragma unroll
      for (int tj = 0; tj < 4; ++tj) {
        float l2 = fmaxf(sqp + sqq[tj] - 2.f * acc[ti][tj][rg], 0.f);
        float y = __expf(-l2 * cinv);
        float kv = y;
        y *= y; kv += y;
        y *= y; kv += y;
        y *= y; kv += y;
        y *= y; kv += y;
        float wgt;
        if (is_st)
          wgt = sp * Vsh[(wc + tj * 16 + mrow) * 40 + lp];
        else
          wgt = (lp == labq[tj]) ? sp * sdq[tj] : 0.f;
        float f = 2.f;
        if (ondiag) {
          int q = q0 + wc + tj * 16 + mrow;
          f = (q > p) ? 2.f : ((q == p) ? 1.f : 0.f);
        }
        local += wgt * kv * f;
      }
    }
  }
  double dl = (double)local;
#pragma unroll
  for (int off = 32; off; off >>= 1) dl += __shfl_down(dl, off, 64);
  if (lane == 0) red[w] = dl;
  __syncthreads();
  if (tid == 0) atomicAdd(&ws->acc_loss, red[0] + red[1] + red[2] + red[3]);
}

// TT blocks: 32x32 tile triangle over target rows.  528 blocks.
__global__ __launch_bounds__(256, 2) void k3_tt(WS* __restrict__ ws) {
  int tid = threadIdx.x, w = tid >> 6;
  int lane = tid & 63;
  int lin = blockIdx.x;
  int bp = 0;
  while (32 * (bp + 1) - ((bp + 1) * bp) / 2 <= lin) ++bp;
  int bq = bp + (lin - (32 * bp - (bp * (bp - 1)) / 2));
  int p0 = B + bp * 128, q0 = B + bq * 128;

  __shared__ __align__(16) unsigned short Ash[2 * 128 * 32];
  __shared__ __align__(16) unsigned short Bsh[2 * 128 * 32];
  __shared__ double red[4];

  const int wr = (w >> 1) * 64, wc = (w & 1) * 64;
  const int mrow = lane & 15, quad = lane >> 4;
  f32x4 acc[4][4], wacc[4][4];
#pragma unroll
  for (int i = 0; i < 4; ++i)
#pragma unroll
    for (int j = 0; j < 4; ++j) {
      acc[i][j] = (f32x4){0.f, 0.f, 0.f, 0.f};
      wacc[i][j] = (f32x4){0.f, 0.f, 0.f, 0.f};
    }

  const unsigned short* Thi = ws->Thi;
  int rA = tid >> 2, cp8 = (tid & 3) * 8;
  unsigned short* ldsA = Ash + w * 512;
  unsigned short* ldsB = Bsh + w * 512;

  FEATURE_LOOP(p0, q0)

  // weight chunk: bf16 v rows, K=32
  __syncthreads();
  {
    const unsigned short* gA = ws->vhi + (size_t)(p0 + rA) * 32 + cp8;
    GLD16(gA, ldsA);
    GLD16(gA + (size_t)64 * 32, ldsA + 2048);
    const unsigned short* gB = ws->vhi + (size_t)(q0 + rA) * 32 + cp8;
    GLD16(gB, ldsB);
    GLD16(gB + (size_t)64 * 32, ldsB + 2048);
  }
  __syncthreads();
  {
    bf16x8 af[4], bfr[4];
#pragma unroll
    for (int ti = 0; ti < 4; ++ti)
      af[ti] = *(const bf16x8*)(Ash + (wr + ti * 16 + mrow) * 32 + quad * 8);
#pragma unroll
    for (int tj = 0; tj < 4; ++tj)
      bfr[tj] = *(const bf16x8*)(Bsh + (wc + tj * 16 + mrow) * 32 + quad * 8);
#pragma unroll
    for (int ti = 0; ti < 4; ++ti)
#pragma unroll
      for (int tj = 0; tj < 4; ++tj)
        wacc[ti][tj] = __builtin_amdgcn_mfma_f32_16x16x32_bf16(
            af[ti], bfr[tj], wacc[ti][tj], 0, 0, 0);
  }

  float cinv = ws->inv_d4;
  float sqq[4];
#pragma unroll
  for (int tj = 0; tj < 4; ++tj) sqq[tj] = ws->sq[q0 + wc + tj * 16 + mrow];
  bool ondiag = (bp == bq);
  float local = 0.f;
#pragma unroll
  for (int ti = 0; ti < 4; ++ti) {
#pragma unroll
    for (int rg = 0; rg < 4; ++rg) {
      int p = p0 + wr + ti * 16 + quad * 4 + rg;
      float sqp = ws->sq[p];
#pragma unroll
      for (int tj = 0; tj < 4; ++tj) {
        float l2 = fmaxf(sqp + sqq[tj] - 2.f * acc[ti][tj][rg], 0.f);
        float y = __expf(-l2 * cinv);
        float kv = y;
        y *= y; kv += y;
        y *= y; kv += y;
        y *= y; kv += y;
        y *= y; kv += y;
        float f = 2.f;
        if (ondiag) {
          int q = q0 + wc + tj * 16 + mrow;
          f = (q > p) ? 2.f : ((q == p) ? 1.f : 0.f);
        }
        local += wacc[ti][tj][rg] * kv * f;
      }
    }
  }
  double dl = (double)local;
#pragma unroll
  for (int off = 32; off; off >>= 1) dl += __shfl_down(dl, off, 64);
  if (lane == 0) red[w] = dl;
  __syncthreads();
  if (tid == 0) atomicAdd(&ws->acc_loss, red[0] + red[1] + red[2] + red[3]);
}

__global__ void k4_out(WS* __restrict__ ws, float* __restrict__ out) {
  out[0] = (float)(ws->acc_loss * (double)ws->inv_n_idx);
}

extern "C" void kernel_launch(void* const* d_in, const int* in_sizes, int n_in,
                              void* d_out, int out_size, void* d_ws, size_t ws_size,
                              hipStream_t stream) {
  const float* src = (const float*)d_in[0];
  const float* tgt = (const float*)d_in[1];
  const int* s_label = (const int*)d_in[2];
  const float* t_label = (const float*)d_in[3];
  float* out = (float*)d_out;
  WS* ws = (WS*)d_ws;  // ~5.9 MB

  k0_init<<<1, 64, 0, stream>>>(ws);
  kA1_stats<<<16, 256, 0, stream>>>(s_label, t_label, ws);
  kA2_final<<<1, 64, 0, stream>>>(ws);
  kB_prep<<<256, 256, 0, stream>>>(src, tgt, s_label, t_label, ws);
  kC_bw<<<1, 256, 0, stream>>>(ws);
  k3_tt<<<528, 256, 0, stream>>>(ws);
  k3_ss_st<<<1552, 256, 0, stream>>>(ws);
  k4_out<<<1, 1, 0, stream>>>(ws, out);
}

// Round 4
// 194.836 us; speedup vs baseline: 3.1573x; 1.2160x over previous
//
#include <hip/hip_runtime.h>

// LMMD loss, round 4: merged tile-pair kernel, 4 blocks/CU.
// loss = (1/n_idx) * sum_{p<=q} f_pq * w_pq * K(p,q),  f=2 off-diag, 1 diag
//   v_i = s_vec[i] (i<B), v_{B+j} = -t_vec[j]
//   K = sum_t y^(2^t), y = exp(-relu(l2)/d4), d4 = largest denom
// Features: bf16 MFMA (hi-only; verified rounds 2-3).
// Weights: SS lookup (exact) / ST LDS gather (bf16) / TT precomputed bf16 tiles.

#define B 4096
#define D 256
#define C 31
#define N2 8192
#define NTILE 64                       // 128-row tiles over 2B rows
#define NBLK (NTILE * (NTILE + 1) / 2) // 2080
#define NTT (32 * 33 / 2)              // 528 TT tile pairs

typedef __attribute__((ext_vector_type(8))) short bf16x8;
typedef __attribute__((ext_vector_type(4))) float f32x4;

struct WS {
  double acc_loss;
  int s_cnt[32];
  float t_cnt[32];
  int t_pres[32];
  float s_div[32], t_div[32];
  float inv_n_idx;
  float inv_d4;
  float sq[N2];
  int slab[N2];
  float sdv[N2];
  float Mpart[256 * 256];
  alignas(16) unsigned short Thi[(size_t)N2 * D];   // bf16 features
  alignas(16) unsigned short vhi[(size_t)N2 * 32];  // bf16 v rows
  alignas(16) float v[(size_t)N2 * 32];             // exact f32 v rows
  alignas(16) unsigned short wtt[(size_t)NTT * 16384];  // bf16 TT weight tiles
};

static __device__ __forceinline__ unsigned short f2bf(float f) {
  unsigned int u = __float_as_uint(f);
  return (unsigned short)((u + 0x7fffu + ((u >> 16) & 1u)) >> 16);  // RNE
}
static __device__ __forceinline__ float bf2f(unsigned short s) {
  return __uint_as_float(((unsigned int)s) << 16);
}

#define GLD16(gsrc, ldst)                                                     \
  __builtin_amdgcn_global_load_lds(                                           \
      (const __attribute__((address_space(1))) void*)(gsrc),                  \
      (__attribute__((address_space(3))) void*)(ldst), 16, 0, 0)

__global__ void k0_init(WS* __restrict__ ws) {
  int tid = threadIdx.x;  // 64
  if (tid == 0) ws->acc_loss = 0.0;
  if (tid < 32) {
    ws->s_cnt[tid] = 0;
    ws->t_cnt[tid] = 0.f;
    ws->t_pres[tid] = 0;
  }
}

__global__ void kA1_stats(const int* __restrict__ s_label,
                          const float* __restrict__ t_label,
                          WS* __restrict__ ws) {
  __shared__ int ls[32];
  __shared__ float lt[32];
  __shared__ int lpres[32];
  int tid = threadIdx.x, lane = tid & 63;  // 256, 16 blocks
  if (tid < 32) { ls[tid] = 0; lt[tid] = 0.f; lpres[tid] = 0; }
  __syncthreads();
  int row = blockIdx.x * 256 + tid;
  atomicAdd(&ls[s_label[row]], 1);
  const float* r = t_label + (size_t)row * C;
  float best = -1e30f;
  int barg = 0;
#pragma unroll
  for (int c = 0; c < C; ++c) {
    float x = r[c];
    if (x > best) { best = x; barg = c; }  // first-max == jnp.argmax
    float s = x;
#pragma unroll
    for (int off = 32; off; off >>= 1) s += __shfl_down(s, off, 64);
    if (lane == 0) atomicAdd(&lt[c], s);  // only 4-way contention
  }
  lpres[barg] = 1;  // benign race
  __syncthreads();
  if (tid < 32) {
    if (ls[tid]) atomicAdd(&ws->s_cnt[tid], ls[tid]);
    atomicAdd(&ws->t_cnt[tid], lt[tid]);
    if (lpres[tid]) ws->t_pres[tid] = 1;
  }
}

__global__ void kA2_final(WS* __restrict__ ws) {
  int tid = threadIdx.x;  // 64
  int m = 0;
  if (tid < 32) {
    int cnt = ws->s_cnt[tid];
    m = (tid < C) && (cnt > 0) && (ws->t_pres[tid] != 0);
    ws->s_div[tid] = m ? 1.f / (float)cnt : 0.f;
    float t = ws->t_cnt[tid];
    float ta = (t == 0.f) ? 100.f : t;
    ws->t_div[tid] = m ? 1.f / ta : 0.f;
  }
  unsigned long long bal = __ballot(m);
  if (tid == 0) ws->inv_n_idx = 1.f / fmaxf((float)__popcll(bal), 1.f);
}

__global__ __launch_bounds__(256) void kB_prep(const float* __restrict__ src,
                                               const float* __restrict__ tgt,
                                               const int* __restrict__ s_label,
                                               const float* __restrict__ t_label,
                                               WS* __restrict__ ws) {
  int tid = threadIdx.x, w = tid >> 6, lane = tid & 63;
  int r0 = blockIdx.x * 32;
  __shared__ float rsq[32];
  __shared__ float colp[4][256];
  float ca0 = 0.f, ca1 = 0.f, ca2 = 0.f, ca3 = 0.f;
#pragma unroll
  for (int i = 0; i < 8; ++i) {
    int rr = w * 8 + i;
    int p = r0 + rr;
    const float* rp = (p < B) ? src + (size_t)p * D : tgt + (size_t)(p - B) * D;
    float4 x = *(const float4*)(rp + lane * 4);
    ushort4 hv;
    hv.x = f2bf(x.x); hv.y = f2bf(x.y); hv.z = f2bf(x.z); hv.w = f2bf(x.w);
    *(ushort4*)(&ws->Thi[(size_t)p * D + lane * 4]) = hv;
    ca0 += x.x; ca1 += x.y; ca2 += x.z; ca3 += x.w;
    float s = x.x * x.x + x.y * x.y + x.z * x.z + x.w * x.w;
#pragma unroll
    for (int off = 32; off; off >>= 1) s += __shfl_down(s, off, 64);
    if (lane == 0) rsq[rr] = s;
  }
  colp[w][lane * 4 + 0] = ca0;
  colp[w][lane * 4 + 1] = ca1;
  colp[w][lane * 4 + 2] = ca2;
  colp[w][lane * 4 + 3] = ca3;
  __syncthreads();
  if (tid < 32) {
    int p = r0 + tid;
    ws->sq[p] = rsq[tid];
    if (p < B) {
      int lb = s_label[p];
      ws->slab[p] = lb;
      ws->sdv[p] = ws->s_div[lb];
    } else {
      ws->slab[p] = 0;
      ws->sdv[p] = 0.f;
    }
  }
  ws->Mpart[(size_t)blockIdx.x * 256 + tid] =
      colp[0][tid] + colp[1][tid] + colp[2][tid] + colp[3][tid];
  int vr = tid >> 3, cb = (tid & 7) * 4;
  int p = r0 + vr;
  float vals[4];
#pragma unroll
  for (int j = 0; j < 4; ++j) {
    int c = cb + j;
    float val = 0.f;
    if (c < C) {
      if (p < B)
        val = (s_label[p] == c) ? ws->s_div[c] : 0.f;
      else
        val = -t_label[(size_t)(p - B) * C + c] * ws->t_div[c];
    }
    vals[j] = val;
  }
  float4 vf; vf.x = vals[0]; vf.y = vals[1]; vf.z = vals[2]; vf.w = vals[3];
  *(float4*)(&ws->v[(size_t)p * 32 + cb]) = vf;
  ushort4 vh;
  vh.x = f2bf(vals[0]); vh.y = f2bf(vals[1]);
  vh.z = f2bf(vals[2]); vh.w = f2bf(vals[3]);
  *(ushort4*)(&ws->vhi[(size_t)p * 32 + cb]) = vh;
}

__global__ void kC_bw(WS* __restrict__ ws) {
  int tid = threadIdx.x;  // 256
  double s = 0.0;
  for (int p = tid; p < N2; p += 256) s += (double)ws->sq[p];
  double col = 0.0;
  for (int b = 0; b < 256; ++b) col += (double)ws->Mpart[(size_t)b * 256 + tid];
  double m2 = col * col;
#pragma unroll
  for (int off = 32; off; off >>= 1) {
    s += __shfl_down(s, off, 64);
    m2 += __shfl_down(m2, off, 64);
  }
  __shared__ double ps[4], pm[4];
  if ((tid & 63) == 0) { ps[tid >> 6] = s; pm[tid >> 6] = m2; }
  __syncthreads();
  if (tid == 0) {
    double S = ps[0] + ps[1] + ps[2] + ps[3];
    double M2 = pm[0] + pm[1] + pm[2] + pm[3];
    double n = (double)N2;
    double sum_l2 = 2.0 * n * S - 2.0 * M2;
    double bw = sum_l2 / (n * n - n);
    bw = fmax(bw, 1e-6) * 0.25;
    double dc4 = fmax(bw * 16.0, 1e-6);
    ws->inv_d4 = (float)(1.0 / dc4);
  }
}

// Precompute TT weight tiles (bf16, stored in C-fragment order).
__global__ __launch_bounds__(256, 2) void kW_tt(WS* __restrict__ ws) {
  int tid = threadIdx.x, w = tid >> 6, lane = tid & 63;
  int lin = blockIdx.x;
  int tp = 0;
  while (32 * (tp + 1) - ((tp + 1) * tp) / 2 <= lin) ++tp;
  int tq = tp + (lin - (32 * tp - (tp * (tp - 1)) / 2));
  int p0 = B + tp * 128, q0 = B + tq * 128;

  __shared__ __align__(16) unsigned short Ash[128 * 32];
  __shared__ __align__(16) unsigned short Bsh[128 * 32];
  const int wr = (w >> 1) * 64, wc = (w & 1) * 64;
  const int mrow = lane & 15, quad = lane >> 4;
  f32x4 acc[4][4];
#pragma unroll
  for (int i = 0; i < 4; ++i)
#pragma unroll
    for (int j = 0; j < 4; ++j) acc[i][j] = (f32x4){0.f, 0.f, 0.f, 0.f};

  int rA = tid >> 2, cp8 = (tid & 3) * 8;
  unsigned short* ldsA = Ash + w * 512;
  unsigned short* ldsB = Bsh + w * 512;
  const unsigned short* gA = ws->vhi + (size_t)(p0 + rA) * 32 + cp8;
  const unsigned short* gB = ws->vhi + (size_t)(q0 + rA) * 32 + cp8;
  GLD16(gA, ldsA);
  GLD16(gA + (size_t)64 * 32, ldsA + 2048);
  GLD16(gB, ldsB);
  GLD16(gB + (size_t)64 * 32, ldsB + 2048);
  __syncthreads();
  {
    bf16x8 af[4], bfr[4];
#pragma unroll
    for (int ti = 0; ti < 4; ++ti)
      af[ti] = *(const bf16x8*)(Ash + (wr + ti * 16 + mrow) * 32 + quad * 8);
#pragma unroll
    for (int tj = 0; tj < 4; ++tj)
      bfr[tj] = *(const bf16x8*)(Bsh + (wc + tj * 16 + mrow) * 32 + quad * 8);
#pragma unroll
    for (int ti = 0; ti < 4; ++ti)
#pragma unroll
      for (int tj = 0; tj < 4; ++tj)
        acc[ti][tj] = __builtin_amdgcn_mfma_f32_16x16x32_bf16(
            af[ti], bfr[tj], acc[ti][tj], 0, 0, 0);
  }
  unsigned short* out = ws->wtt + (size_t)lin * 16384 + tid * 64;
#pragma unroll
  for (int ti = 0; ti < 4; ++ti)
#pragma unroll
    for (int tj = 0; tj < 4; ++tj) {
      ushort4 u;
      u.x = f2bf(acc[ti][tj][0]);
      u.y = f2bf(acc[ti][tj][1]);
      u.z = f2bf(acc[ti][tj][2]);
      u.w = f2bf(acc[ti][tj][3]);
      *(ushort4*)(out + (ti * 4 + tj) * 4) = u;
    }
}

// ---- epilogue helpers (forceinlined; KIND 0=SS, 1=ST) ----
template <int KIND, bool DIAG>
static __device__ __forceinline__ float epi_ss_st(
    const f32x4 (&acc)[4][4], const WS* __restrict__ ws,
    const unsigned short* Vsw, int p0, int q0, int wr, int wc, int mrow,
    int quad) {
  float cinv = ws->inv_d4;
  float k2 = 2.f * cinv;
  float cq[4], sdq[4];
  int lq[4];
#pragma unroll
  for (int tj = 0; tj < 4; ++tj) {
    int q = q0 + wc + tj * 16 + mrow;
    cq[tj] = -cinv * ws->sq[q];
    if (KIND == 0) {
      lq[tj] = ws->slab[q];
      sdq[tj] = ws->sdv[q];
    }
  }
  float local = 0.f;
#pragma unroll
  for (int ti = 0; ti < 4; ++ti) {
#pragma unroll
    for (int rg = 0; rg < 4; ++rg) {
      int p = p0 + wr + ti * 16 + quad * 4 + rg;
      float cpl = -cinv * ws->sq[p];
      int lp = ws->slab[p];
      float sp = ws->sdv[p];
#pragma unroll
      for (int tj = 0; tj < 4; ++tj) {
        float z = fminf(fmaf(k2, acc[ti][tj][rg], cpl + cq[tj]), 0.f);
        float y = __expf(z);
        float kv = y;
        y *= y; kv += y;
        y *= y; kv += y;
        y *= y; kv += y;
        y *= y; kv += y;
        float wv;
        if (KIND == 0) {
          wv = (lp == lq[tj]) ? sp * sdq[tj] : 0.f;
        } else {
          int ql = wc + tj * 16 + mrow;
          wv = sp * bf2f(Vsw[ql * 32 + ((lp + ql) & 31)]);
        }
        if (DIAG) {
          int q = q0 + wc + tj * 16 + mrow;
          float f = (q > p) ? 2.f : ((q == p) ? 1.f : 0.f);
          local = fmaf(wv * f, kv, local);
        } else {
          local = fmaf(wv, kv, local);
        }
      }
    }
  }
  if (!DIAG) local *= 2.f;
  return local;
}

template <bool DIAG>
static __device__ __forceinline__ float epi_tt(const f32x4 (&acc)[4][4],
                                               const WS* __restrict__ ws,
                                               const unsigned short* wttp,
                                               int p0, int q0, int wr, int wc,
                                               int mrow, int quad) {
  float cinv = ws->inv_d4;
  float k2 = 2.f * cinv;
  float cq[4];
#pragma unroll
  for (int tj = 0; tj < 4; ++tj)
    cq[tj] = -cinv * ws->sq[q0 + wc + tj * 16 + mrow];
  float cp[16];
#pragma unroll
  for (int ti = 0; ti < 4; ++ti)
#pragma unroll
    for (int rg = 0; rg < 4; ++rg)
      cp[ti * 4 + rg] = -cinv * ws->sq[p0 + wr + ti * 16 + quad * 4 + rg];
  float local = 0.f;
#pragma unroll
  for (int ti = 0; ti < 4; ++ti) {
#pragma unroll
    for (int tj = 0; tj < 4; ++tj) {
      ushort4 u = *(const ushort4*)(wttp + (ti * 4 + tj) * 4);
      float wf[4] = {bf2f(u.x), bf2f(u.y), bf2f(u.z), bf2f(u.w)};
#pragma unroll
      for (int rg = 0; rg < 4; ++rg) {
        float z = fminf(fmaf(k2, acc[ti][tj][rg], cp[ti * 4 + rg] + cq[tj]), 0.f);
        float y = __expf(z);
        float kv = y;
        y *= y; kv += y;
        y *= y; kv += y;
        y *= y; kv += y;
        y *= y; kv += y;
        if (DIAG) {
          int p = p0 + wr + ti * 16 + quad * 4 + rg;
          int q = q0 + wc + tj * 16 + mrow;
          float f = (q > p) ? 2.f : ((q == p) ? 1.f : 0.f);
          local = fmaf(wf[rg] * f, kv, local);
        } else {
          local = fmaf(wf[rg], kv, local);
        }
      }
    }
  }
  if (!DIAG) local *= 2.f;
  return local;
}

// Merged main kernel: all 2080 upper-tri 128x128 tile pairs.
__global__ __launch_bounds__(256, 4) void k3_main(WS* __restrict__ ws) {
  int tid = threadIdx.x, w = tid >> 6, lane = tid & 63;
  int lin = blockIdx.x;
  int bp = 0;
  while (NTILE * (bp + 1) - ((bp + 1) * bp) / 2 <= lin) ++bp;
  int bq = bp + (lin - (NTILE * bp - (bp * (bp - 1)) / 2));
  int p0 = bp * 128, q0 = bq * 128;

  __shared__ __align__(16) unsigned short Ash[2 * 128 * 32];  // 16 KB
  __shared__ __align__(16) unsigned short Bsh[2 * 128 * 32];  // 16 KB
  __shared__ unsigned short Vsw[128 * 32];                    // 8 KB (ST only)
  // total 40960 B -> 4 blocks/CU; reduction scratch aliases Ash

  const int wr = (w >> 1) * 64, wc = (w & 1) * 64;
  const int mrow = lane & 15, quad = lane >> 4;
  f32x4 acc[4][4];
#pragma unroll
  for (int i = 0; i < 4; ++i)
#pragma unroll
    for (int j = 0; j < 4; ++j) acc[i][j] = (f32x4){0.f, 0.f, 0.f, 0.f};

  const unsigned short* Thi = ws->Thi;
  int rA = tid >> 2, cp8 = (tid & 3) * 8;
  unsigned short* ldsA = Ash + w * 512;
  unsigned short* ldsB = Bsh + w * 512;

  for (int s = 0; s < 4; ++s) {
    int ks = s * 64;
    __syncthreads();
#pragma unroll
    for (int c = 0; c < 2; ++c) {
      const unsigned short* gA = Thi + (size_t)(p0 + rA) * D + ks + c * 32 + cp8;
      GLD16(gA, ldsA + c * 4096);
      GLD16(gA + (size_t)64 * D, ldsA + c * 4096 + 2048);
      const unsigned short* gB = Thi + (size_t)(q0 + rA) * D + ks + c * 32 + cp8;
      GLD16(gB, ldsB + c * 4096);
      GLD16(gB + (size_t)64 * D, ldsB + c * 4096 + 2048);
    }
    __syncthreads();
#pragma unroll
    for (int c = 0; c < 2; ++c) {
      bf16x8 af[4], bfr[4];
#pragma unroll
      for (int ti = 0; ti < 4; ++ti)
        af[ti] = *(const bf16x8*)(Ash + c * 4096 + (wr + ti * 16 + mrow) * 32 +
                                  quad * 8);
#pragma unroll
      for (int tj = 0; tj < 4; ++tj)
        bfr[tj] = *(const bf16x8*)(Bsh + c * 4096 + (wc + tj * 16 + mrow) * 32 +
                                   quad * 8);
#pragma unroll
      for (int ti = 0; ti < 4; ++ti)
#pragma unroll
        for (int tj = 0; tj < 4; ++tj)
          acc[ti][tj] = __builtin_amdgcn_mfma_f32_16x16x32_bf16(
              af[ti], bfr[tj], acc[ti][tj], 0, 0, 0);
    }
  }

  bool is_ss = (bq < 32);
  bool is_tt = (bp >= 32);
  if (!is_ss && !is_tt) {
    // ST: stage rotate-swizzled bf16 v rows of the q (target) tile.
    int r = tid >> 1, h = (tid & 1) * 16;
    const float* vrow = ws->v + (size_t)(q0 + r) * 32 + h;
#pragma unroll
    for (int j = 0; j < 16; ++j)
      Vsw[r * 32 + ((h + j + r) & 31)] = f2bf(vrow[j]);
  }
  __syncthreads();  // feature-loop LDS reads done; Vsw staged

  float local;
  if (is_ss) {
    if (bp == bq)
      local = epi_ss_st<0, true>(acc, ws, Vsw, p0, q0, wr, wc, mrow, quad);
    else
      local = epi_ss_st<0, false>(acc, ws, Vsw, p0, q0, wr, wc, mrow, quad);
  } else if (!is_tt) {
    local = epi_ss_st<1, false>(acc, ws, Vsw, p0, q0, wr, wc, mrow, quad);
  } else {
    int tp = bp - 32, tq = bq - 32;
    int ttlin = 32 * tp - (tp * (tp - 1)) / 2 + (tq - tp);
    const unsigned short* wttp = ws->wtt + (size_t)ttlin * 16384 + tid * 64;
    if (bp == bq)
      local = epi_tt<true>(acc, ws, wttp, p0, q0, wr, wc, mrow, quad);
    else
      local = epi_tt<false>(acc, ws, wttp, p0, q0, wr, wc, mrow, quad);
  }

  double dl = (double)local;
#pragma unroll
  for (int off = 32; off; off >>= 1) dl += __shfl_down(dl, off, 64);
  double* red = (double*)Ash;  // safe: all Ash reads completed pre-barrier
  if (lane == 0) red[w] = dl;
  __syncthreads();
  if (tid == 0) atomicAdd(&ws->acc_loss, red[0] + red[1] + red[2] + red[3]);
}

__global__ void k4_out(WS* __restrict__ ws, float* __restrict__ out) {
  out[0] = (float)(ws->acc_loss * (double)ws->inv_n_idx);
}

extern "C" void kernel_launch(void* const* d_in, const int* in_sizes, int n_in,
                              void* d_out, int out_size, void* d_ws, size_t ws_size,
                              hipStream_t stream) {
  const float* src = (const float*)d_in[0];
  const float* tgt = (const float*)d_in[1];
  const int* s_label = (const int*)d_in[2];
  const float* t_label = (const float*)d_in[3];
  float* out = (float*)d_out;
  WS* ws = (WS*)d_ws;  // ~23.2 MB

  k0_init<<<1, 64, 0, stream>>>(ws);
  kA1_stats<<<16, 256, 0, stream>>>(s_label, t_label, ws);
  kA2_final<<<1, 64, 0, stream>>>(ws);
  kB_prep<<<256, 256, 0, stream>>>(src, tgt, s_label, t_label, ws);
  kC_bw<<<1, 256, 0, stream>>>(ws);
  kW_tt<<<NTT, 256, 0, stream>>>(ws);
  k3_main<<<NBLK, 256, 0, stream>>>(ws);
  k4_out<<<1, 1, 0, stream>>>(ws, out);
}

// Round 6
// 183.207 us; speedup vs baseline: 3.3577x; 1.0635x over previous
//
#include <hip/hip_runtime.h>

// LMMD loss, round 6: round-4 kernel (known good) + XCD-aware tile schedule.
// ONLY change vs round 4: k3_main's blockIdx -> (bp,bq) mapping.
// loss = (1/n_idx) * sum_{p<=q} f_pq * w_pq * K(p,q),  f=2 off-diag, 1 diag
//   v_i = s_vec[i] (i<B), v_{B+j} = -t_vec[j]
//   K = sum_t y^(2^t), y = exp(-relu(l2)/d4), d4 = largest denom
// Features: bf16 MFMA (hi-only; exact-match verified rounds 2-4).
// Weights: SS lookup (exact) / ST LDS gather (bf16) / TT precomputed bf16 tiles.

#define B 4096
#define D 256
#define C 31
#define N2 8192
#define NTILE 64                       // 128-row tiles over 2B rows
#define NBLK (NTILE * (NTILE + 1) / 2) // 2080
#define NTT (32 * 33 / 2)              // 528 TT tile pairs

typedef __attribute__((ext_vector_type(8))) short bf16x8;
typedef __attribute__((ext_vector_type(4))) float f32x4;

struct WS {
  double acc_loss;
  int s_cnt[32];
  float t_cnt[32];
  int t_pres[32];
  float s_div[32], t_div[32];
  float inv_n_idx;
  float inv_d4;
  float sq[N2];
  int slab[N2];
  float sdv[N2];
  float Mpart[256 * 256];
  alignas(16) unsigned short Thi[(size_t)N2 * D];   // bf16 features
  alignas(16) unsigned short vhi[(size_t)N2 * 32];  // bf16 v rows
  alignas(16) float v[(size_t)N2 * 32];             // exact f32 v rows
  alignas(16) unsigned short wtt[(size_t)NTT * 16384];  // bf16 TT weight tiles
};

static __device__ __forceinline__ unsigned short f2bf(float f) {
  unsigned int u = __float_as_uint(f);
  return (unsigned short)((u + 0x7fffu + ((u >> 16) & 1u)) >> 16);  // RNE
}
static __device__ __forceinline__ float bf2f(unsigned short s) {
  return __uint_as_float(((unsigned int)s) << 16);
}

#define GLD16(gsrc, ldst)                                                     \
  __builtin_amdgcn_global_load_lds(                                           \
      (const __attribute__((address_space(1))) void*)(gsrc),                  \
      (__attribute__((address_space(3))) void*)(ldst), 16, 0, 0)

__global__ void k0_init(WS* __restrict__ ws) {
  int tid = threadIdx.x;  // 64
  if (tid == 0) ws->acc_loss = 0.0;
  if (tid < 32) {
    ws->s_cnt[tid] = 0;
    ws->t_cnt[tid] = 0.f;
    ws->t_pres[tid] = 0;
  }
}

__global__ void kA1_stats(const int* __restrict__ s_label,
                          const float* __restrict__ t_label,
                          WS* __restrict__ ws) {
  __shared__ int ls[32];
  __shared__ float lt[32];
  __shared__ int lpres[32];
  int tid = threadIdx.x, lane = tid & 63;  // 256, 16 blocks
  if (tid < 32) { ls[tid] = 0; lt[tid] = 0.f; lpres[tid] = 0; }
  __syncthreads();
  int row = blockIdx.x * 256 + tid;
  atomicAdd(&ls[s_label[row]], 1);
  const float* r = t_label + (size_t)row * C;
  float best = -1e30f;
  int barg = 0;
#pragma unroll
  for (int c = 0; c < C; ++c) {
    float x = r[c];
    if (x > best) { best = x; barg = c; }  // first-max == jnp.argmax
    float s = x;
#pragma unroll
    for (int off = 32; off; off >>= 1) s += __shfl_down(s, off, 64);
    if (lane == 0) atomicAdd(&lt[c], s);
  }
  lpres[barg] = 1;  // benign race
  __syncthreads();
  if (tid < 32) {
    if (ls[tid]) atomicAdd(&ws->s_cnt[tid], ls[tid]);
    atomicAdd(&ws->t_cnt[tid], lt[tid]);
    if (lpres[tid]) ws->t_pres[tid] = 1;
  }
}

__global__ void kA2_final(WS* __restrict__ ws) {
  int tid = threadIdx.x;  // 64
  int m = 0;
  if (tid < 32) {
    int cnt = ws->s_cnt[tid];
    m = (tid < C) && (cnt > 0) && (ws->t_pres[tid] != 0);
    ws->s_div[tid] = m ? 1.f / (float)cnt : 0.f;
    float t = ws->t_cnt[tid];
    float ta = (t == 0.f) ? 100.f : t;
    ws->t_div[tid] = m ? 1.f / ta : 0.f;
  }
  unsigned long long bal = __ballot(m);
  if (tid == 0) ws->inv_n_idx = 1.f / fmaxf((float)__popcll(bal), 1.f);
}

__global__ __launch_bounds__(256) void kB_prep(const float* __restrict__ src,
                                               const float* __restrict__ tgt,
                                               const int* __restrict__ s_label,
                                               const float* __restrict__ t_label,
                                               WS* __restrict__ ws) {
  int tid = threadIdx.x, w = tid >> 6, lane = tid & 63;
  int r0 = blockIdx.x * 32;
  __shared__ float rsq[32];
  __shared__ float colp[4][256];
  float ca0 = 0.f, ca1 = 0.f, ca2 = 0.f, ca3 = 0.f;
#pragma unroll
  for (int i = 0; i < 8; ++i) {
    int rr = w * 8 + i;
    int p = r0 + rr;
    const float* rp = (p < B) ? src + (size_t)p * D : tgt + (size_t)(p - B) * D;
    float4 x = *(const float4*)(rp + lane * 4);
    ushort4 hv;
    hv.x = f2bf(x.x); hv.y = f2bf(x.y); hv.z = f2bf(x.z); hv.w = f2bf(x.w);
    *(ushort4*)(&ws->Thi[(size_t)p * D + lane * 4]) = hv;
    ca0 += x.x; ca1 += x.y; ca2 += x.z; ca3 += x.w;
    float s = x.x * x.x + x.y * x.y + x.z * x.z + x.w * x.w;
#pragma unroll
    for (int off = 32; off; off >>= 1) s += __shfl_down(s, off, 64);
    if (lane == 0) rsq[rr] = s;
  }
  colp[w][lane * 4 + 0] = ca0;
  colp[w][lane * 4 + 1] = ca1;
  colp[w][lane * 4 + 2] = ca2;
  colp[w][lane * 4 + 3] = ca3;
  __syncthreads();
  if (tid < 32) {
    int p = r0 + tid;
    ws->sq[p] = rsq[tid];
    if (p < B) {
      int lb = s_label[p];
      ws->slab[p] = lb;
      ws->sdv[p] = ws->s_div[lb];
    } else {
      ws->slab[p] = 0;
      ws->sdv[p] = 0.f;
    }
  }
  ws->Mpart[(size_t)blockIdx.x * 256 + tid] =
      colp[0][tid] + colp[1][tid] + colp[2][tid] + colp[3][tid];
  int vr = tid >> 3, cb = (tid & 7) * 4;
  int p = r0 + vr;
  float vals[4];
#pragma unroll
  for (int j = 0; j < 4; ++j) {
    int c = cb + j;
    float val = 0.f;
    if (c < C) {
      if (p < B)
        val = (s_label[p] == c) ? ws->s_div[c] : 0.f;
      else
        val = -t_label[(size_t)(p - B) * C + c] * ws->t_div[c];
    }
    vals[j] = val;
  }
  float4 vf; vf.x = vals[0]; vf.y = vals[1]; vf.z = vals[2]; vf.w = vals[3];
  *(float4*)(&ws->v[(size_t)p * 32 + cb]) = vf;
  ushort4 vh;
  vh.x = f2bf(vals[0]); vh.y = f2bf(vals[1]);
  vh.z = f2bf(vals[2]); vh.w = f2bf(vals[3]);
  *(ushort4*)(&ws->vhi[(size_t)p * 32 + cb]) = vh;
}

__global__ void kC_bw(WS* __restrict__ ws) {
  int tid = threadIdx.x;  // 256
  double s = 0.0;
  for (int p = tid; p < N2; p += 256) s += (double)ws->sq[p];
  double col = 0.0;
  for (int b = 0; b < 256; ++b) col += (double)ws->Mpart[(size_t)b * 256 + tid];
  double m2 = col * col;
#pragma unroll
  for (int off = 32; off; off >>= 1) {
    s += __shfl_down(s, off, 64);
    m2 += __shfl_down(m2, off, 64);
  }
  __shared__ double ps[4], pm[4];
  if ((tid & 63) == 0) { ps[tid >> 6] = s; pm[tid >> 6] = m2; }
  __syncthreads();
  if (tid == 0) {
    double S = ps[0] + ps[1] + ps[2] + ps[3];
    double M2 = pm[0] + pm[1] + pm[2] + pm[3];
    double n = (double)N2;
    double sum_l2 = 2.0 * n * S - 2.0 * M2;
    double bw = sum_l2 / (n * n - n);
    bw = fmax(bw, 1e-6) * 0.25;
    double dc4 = fmax(bw * 16.0, 1e-6);
    ws->inv_d4 = (float)(1.0 / dc4);
  }
}

// Precompute TT weight tiles (bf16, stored in C-fragment order).
__global__ __launch_bounds__(256, 2) void kW_tt(WS* __restrict__ ws) {
  int tid = threadIdx.x, w = tid >> 6, lane = tid & 63;
  int lin = blockIdx.x;
  int tp = 0;
  while (32 * (tp + 1) - ((tp + 1) * tp) / 2 <= lin) ++tp;
  int tq = tp + (lin - (32 * tp - (tp * (tp - 1)) / 2));
  int p0 = B + tp * 128, q0 = B + tq * 128;

  __shared__ __align__(16) unsigned short Ash[128 * 32];
  __shared__ __align__(16) unsigned short Bsh[128 * 32];
  const int wr = (w >> 1) * 64, wc = (w & 1) * 64;
  const int mrow = lane & 15, quad = lane >> 4;
  f32x4 acc[4][4];
#pragma unroll
  for (int i = 0; i < 4; ++i)
#pragma unroll
    for (int j = 0; j < 4; ++j) acc[i][j] = (f32x4){0.f, 0.f, 0.f, 0.f};

  int rA = tid >> 2, cp8 = (tid & 3) * 8;
  unsigned short* ldsA = Ash + w * 512;
  unsigned short* ldsB = Bsh + w * 512;
  const unsigned short* gA = ws->vhi + (size_t)(p0 + rA) * 32 + cp8;
  const unsigned short* gB = ws->vhi + (size_t)(q0 + rA) * 32 + cp8;
  GLD16(gA, ldsA);
  GLD16(gA + (size_t)64 * 32, ldsA + 2048);
  GLD16(gB, ldsB);
  GLD16(gB + (size_t)64 * 32, ldsB + 2048);
  __syncthreads();
  {
    bf16x8 af[4], bfr[4];
#pragma unroll
    for (int ti = 0; ti < 4; ++ti)
      af[ti] = *(const bf16x8*)(Ash + (wr + ti * 16 + mrow) * 32 + quad * 8);
#pragma unroll
    for (int tj = 0; tj < 4; ++tj)
      bfr[tj] = *(const bf16x8*)(Bsh + (wc + tj * 16 + mrow) * 32 + quad * 8);
#pragma unroll
    for (int ti = 0; ti < 4; ++ti)
#pragma unroll
      for (int tj = 0; tj < 4; ++tj)
        acc[ti][tj] = __builtin_amdgcn_mfma_f32_16x16x32_bf16(
            af[ti], bfr[tj], acc[ti][tj], 0, 0, 0);
  }
  unsigned short* out = ws->wtt + (size_t)lin * 16384 + tid * 64;
#pragma unroll
  for (int ti = 0; ti < 4; ++ti)
#pragma unroll
    for (int tj = 0; tj < 4; ++tj) {
      ushort4 u;
      u.x = f2bf(acc[ti][tj][0]);
      u.y = f2bf(acc[ti][tj][1]);
      u.z = f2bf(acc[ti][tj][2]);
      u.w = f2bf(acc[ti][tj][3]);
      *(ushort4*)(out + (ti * 4 + tj) * 4) = u;
    }
}

// ---- epilogue helpers (forceinlined; KIND 0=SS, 1=ST) ----
template <int KIND, bool DIAG>
static __device__ __forceinline__ float epi_ss_st(
    const f32x4 (&acc)[4][4], const WS* __restrict__ ws,
    const unsigned short* Vsw, int p0, int q0, int wr, int wc, int mrow,
    int quad) {
  float cinv = ws->inv_d4;
  float k2 = 2.f * cinv;
  float cq[4], sdq[4];
  int lq[4];
#pragma unroll
  for (int tj = 0; tj < 4; ++tj) {
    int q = q0 + wc + tj * 16 + mrow;
    cq[tj] = -cinv * ws->sq[q];
    if (KIND == 0) {
      lq[tj] = ws->slab[q];
      sdq[tj] = ws->sdv[q];
    }
  }
  float local = 0.f;
#pragma unroll
  for (int ti = 0; ti < 4; ++ti) {
#pragma unroll
    for (int rg = 0; rg < 4; ++rg) {
      int p = p0 + wr + ti * 16 + quad * 4 + rg;
      float cpl = -cinv * ws->sq[p];
      int lp = ws->slab[p];
      float sp = ws->sdv[p];
#pragma unroll
      for (int tj = 0; tj < 4; ++tj) {
        float z = fminf(fmaf(k2, acc[ti][tj][rg], cpl + cq[tj]), 0.f);
        float y = __expf(z);
        float kv = y;
        y *= y; kv += y;
        y *= y; kv += y;
        y *= y; kv += y;
        y *= y; kv += y;
        float wv;
        if (KIND == 0) {
          wv = (lp == lq[tj]) ? sp * sdq[tj] : 0.f;
        } else {
          int ql = wc + tj * 16 + mrow;
          wv = sp * bf2f(Vsw[ql * 32 + ((lp + ql) & 31)]);
        }
        if (DIAG) {
          int q = q0 + wc + tj * 16 + mrow;
          float f = (q > p) ? 2.f : ((q == p) ? 1.f : 0.f);
          local = fmaf(wv * f, kv, local);
        } else {
          local = fmaf(wv, kv, local);
        }
      }
    }
  }
  if (!DIAG) local *= 2.f;
  return local;
}

template <bool DIAG>
static __device__ __forceinline__ float epi_tt(const f32x4 (&acc)[4][4],
                                               const WS* __restrict__ ws,
                                               const unsigned short* wttp,
                                               int p0, int q0, int wr, int wc,
                                               int mrow, int quad) {
  float cinv = ws->inv_d4;
  float k2 = 2.f * cinv;
  float cq[4];
#pragma unroll
  for (int tj = 0; tj < 4; ++tj)
    cq[tj] = -cinv * ws->sq[q0 + wc + tj * 16 + mrow];
  float cp[16];
#pragma unroll
  for (int ti = 0; ti < 4; ++ti)
#pragma unroll
    for (int rg = 0; rg < 4; ++rg)
      cp[ti * 4 + rg] = -cinv * ws->sq[p0 + wr + ti * 16 + quad * 4 + rg];
  float local = 0.f;
#pragma unroll
  for (int ti = 0; ti < 4; ++ti) {
#pragma unroll
    for (int tj = 0; tj < 4; ++tj) {
      ushort4 u = *(const ushort4*)(wttp + (ti * 4 + tj) * 4);
      float wf[4] = {bf2f(u.x), bf2f(u.y), bf2f(u.z), bf2f(u.w)};
#pragma unroll
      for (int rg = 0; rg < 4; ++rg) {
        float z = fminf(fmaf(k2, acc[ti][tj][rg], cp[ti * 4 + rg] + cq[tj]), 0.f);
        float y = __expf(z);
        float kv = y;
        y *= y; kv += y;
        y *= y; kv += y;
        y *= y; kv += y;
        y *= y; kv += y;
        if (DIAG) {
          int p = p0 + wr + ti * 16 + quad * 4 + rg;
          int q = q0 + wc + tj * 16 + mrow;
          float f = (q > p) ? 2.f : ((q == p) ? 1.f : 0.f);
          local = fmaf(wf[rg] * f, kv, local);
        } else {
          local = fmaf(wf[rg], kv, local);
        }
      }
    }
  }
  if (!DIAG) local *= 2.f;
  return local;
}

// Merged main kernel: all 2080 upper-tri 128x128 tile pairs.
// ONLY CHANGE vs round 4: XCD-aware (bp,bq) decode. Blocks with lin%8==c
// (same XCD under round-robin dispatch) process a contiguous 260-pair range
// of a band-ordered (8-row bp bands, bq-major) sequence -> same-XCD blocks
// share one B tile per 8 pairs plus a resident 1 MB A band in their L2.
__global__ __launch_bounds__(256, 4) void k3_main(WS* __restrict__ ws) {
  int tid = threadIdx.x, w = tid >> 6, lane = tid & 63;
  int lin0 = blockIdx.x;
  int e = (lin0 & 7) * (NBLK / 8) + (lin0 >> 3);
  int b = 0, nb = 484, rem = e;
  while (rem >= nb) { rem -= nb; ++b; nb -= 64; }
  int base = b * 8;
  int bq_, r;
  if (rem < 36) {  // triangular head of the band (bq within band)
    bq_ = 0;
    while ((bq_ + 1) * (bq_ + 2) / 2 <= rem) ++bq_;
    r = rem - (bq_ * (bq_ + 1)) / 2;
  } else {  // full-height 8-row columns
    int t = rem - 36;
    bq_ = 8 + (t >> 3);
    r = t & 7;
  }
  int bp = base + r, bq = base + bq_;
  int p0 = bp * 128, q0 = bq * 128;

  __shared__ __align__(16) unsigned short Ash[2 * 128 * 32];  // 16 KB
  __shared__ __align__(16) unsigned short Bsh[2 * 128 * 32];  // 16 KB
  __shared__ unsigned short Vsw[128 * 32];                    // 8 KB (ST only)

  const int wr = (w >> 1) * 64, wc = (w & 1) * 64;
  const int mrow = lane & 15, quad = lane >> 4;
  f32x4 acc[4][4];
#pragma unroll
  for (int i = 0; i < 4; ++i)
#pragma unroll
    for (int j = 0; j < 4; ++j) acc[i][j] = (f32x4){0.f, 0.f, 0.f, 0.f};

  const unsigned short* Thi = ws->Thi;
  int rA = tid >> 2, cp8 = (tid & 3) * 8;
  unsigned short* ldsA = Ash + w * 512;
  unsigned short* ldsB = Bsh + w * 512;

  for (int s = 0; s < 4; ++s) {
    int ks = s * 64;
    __syncthreads();
#pragma unroll
    for (int c = 0; c < 2; ++c) {
      const unsigned short* gA = Thi + (size_t)(p0 + rA) * D + ks + c * 32 + cp8;
      GLD16(gA, ldsA + c * 4096);
      GLD16(gA + (size_t)64 * D, ldsA + c * 4096 + 2048);
      const unsigned short* gB = Thi + (size_t)(q0 + rA) * D + ks + c * 32 + cp8;
      GLD16(gB, ldsB + c * 4096);
      GLD16(gB + (size_t)64 * D, ldsB + c * 4096 + 2048);
    }
    __syncthreads();
#pragma unroll
    for (int c = 0; c < 2; ++c) {
      bf16x8 af[4], bfr[4];
#pragma unroll
      for (int ti = 0; ti < 4; ++ti)
        af[ti] = *(const bf16x8*)(Ash + c * 4096 + (wr + ti * 16 + mrow) * 32 +
                                  quad * 8);
#pragma unroll
      for (int tj = 0; tj < 4; ++tj)
        bfr[tj] = *(const bf16x8*)(Bsh + c * 4096 + (wc + tj * 16 + mrow) * 32 +
                                   quad * 8);
#pragma unroll
      for (int ti = 0; ti < 4; ++ti)
#pragma unroll
        for (int tj = 0; tj < 4; ++tj)
          acc[ti][tj] = __builtin_amdgcn_mfma_f32_16x16x32_bf16(
              af[ti], bfr[tj], acc[ti][tj], 0, 0, 0);
    }
  }

  bool is_ss = (bq < 32);
  bool is_tt = (bp >= 32);
  if (!is_ss && !is_tt) {
    // ST: stage rotate-swizzled bf16 v rows of the q (target) tile.
    int rr = tid >> 1, h = (tid & 1) * 16;
    const float* vrow = ws->v + (size_t)(q0 + rr) * 32 + h;
#pragma unroll
    for (int j = 0; j < 16; ++j)
      Vsw[rr * 32 + ((h + j + rr) & 31)] = f2bf(vrow[j]);
  }
  __syncthreads();  // feature-loop LDS reads done; Vsw staged

  float local;
  if (is_ss) {
    if (bp == bq)
      local = epi_ss_st<0, true>(acc, ws, Vsw, p0, q0, wr, wc, mrow, quad);
    else
      local = epi_ss_st<0, false>(acc, ws, Vsw, p0, q0, wr, wc, mrow, quad);
  } else if (!is_tt) {
    local = epi_ss_st<1, false>(acc, ws, Vsw, p0, q0, wr, wc, mrow, quad);
  } else {
    int tp = bp - 32, tq = bq - 32;
    int ttlin = 32 * tp - (tp * (tp - 1)) / 2 + (tq - tp);
    const unsigned short* wttp = ws->wtt + (size_t)ttlin * 16384 + tid * 64;
    if (bp == bq)
      local = epi_tt<true>(acc, ws, wttp, p0, q0, wr, wc, mrow, quad);
    else
      local = epi_tt<false>(acc, ws, wttp, p0, q0, wr, wc, mrow, quad);
  }

  double dl = (double)local;
#pragma unroll
  for (int off = 32; off; off >>= 1) dl += __shfl_down(dl, off, 64);
  double* red = (double*)Ash;  // safe: all Ash reads completed pre-barrier
  if (lane == 0) red[w] = dl;
  __syncthreads();
  if (tid == 0) atomicAdd(&ws->acc_loss, red[0] + red[1] + red[2] + red[3]);
}

__global__ void k4_out(WS* __restrict__ ws, float* __restrict__ out) {
  out[0] = (float)(ws->acc_loss * (double)ws->inv_n_idx);
}

extern "C" void kernel_launch(void* const* d_in, const int* in_sizes, int n_in,
                              void* d_out, int out_size, void* d_ws, size_t ws_size,
                              hipStream_t stream) {
  const float* src = (const float*)d_in[0];
  const float* tgt = (const float*)d_in[1];
  const int* s_label = (const int*)d_in[2];
  const float* t_label = (const float*)d_in[3];
  float* out = (float*)d_out;
  WS* ws = (WS*)d_ws;  // ~23.2 MB

  k0_init<<<1, 64, 0, stream>>>(ws);
  kA1_stats<<<16, 256, 0, stream>>>(s_label, t_label, ws);
  kA2_final<<<1, 64, 0, stream>>>(ws);
  kB_prep<<<256, 256, 0, stream>>>(src, tgt, s_label, t_label, ws);
  kC_bw<<<1, 256, 0, stream>>>(ws);
  kW_tt<<<NTT, 256, 0, stream>>>(ws);
  k3_main<<<NBLK, 256, 0, stream>>>(ws);
  k4_out<<<1, 1, 0, stream>>>(ws, out);
}